// Round 19
// baseline (279.007 us; speedup 1.0000x reference)
//
#include <hip/hip_runtime.h>
#include <hip/hip_fp16.h>
#include <math.h>

#define F_IN 128
#define F_HID 64
#define NWG 256      // partition chunks (= blocks of k_count/k_part)
#define PT 1024      // threads per partition block
#define BSH 7        // dst bucket shift (128 nodes per bucket)
#define BSZ 128
#define BSHS 10      // src bucket shift (1024 nodes per bucket, feeds k_dw LDS acc)
#define BSZS 1024
#define SEGCAP 6144  // max edges per dst-bucket staged in LDS (mean 4096)
#define SUBC 6144    // k_part sub-chunk (LDS-sorted before write-out)

typedef float f32x2 __attribute__((ext_vector_type(2)));
typedef float f32x4 __attribute__((ext_vector_type(4)));
typedef __bf16 bf16x8 __attribute__((ext_vector_type(8)));

// ---- fp8 e4m3 (OCP, gfx950 HW cvt) ----
__device__ __forceinline__ unsigned char f32_to_fp8(float v) {
  unsigned r = __builtin_amdgcn_cvt_pk_fp8_f32(v, v, 0, false);
  return (unsigned char)(r & 0xFFu);
}

// ---- f32 -> bf16 RTNE (bit-manip) ----
__device__ __forceinline__ __bf16 f32_bf16(float f) {
  unsigned u = __float_as_uint(f);
  unsigned r = (u + 0x7FFFu + ((u >> 16) & 1u)) >> 16;
  return __builtin_bit_cast(__bf16, (unsigned short)r);
}

// ---- non-temporal load (evict-first in L2; protects gather working sets) ----
__device__ __forceinline__ int2 nt_i2(const int2* p) {
  long long v = __builtin_nontemporal_load((const long long*)p);
  return make_int2((int)(v & 0xFFFFFFFFll), (int)(v >> 32));
}

// ------- P1: per-(bucket, wg) counts, dst-buckets (128) and src-buckets (1024) -------
__global__ void k_count(const int* __restrict__ src, const int* __restrict__ dst,
                        int* __restrict__ cntAll, int NBD, int NBS, int E) {
  extern __shared__ int sh[];
  int* hD = sh;          // NBD
  int* hS = sh + NBD;    // NBS
  int tid = threadIdx.x, w = blockIdx.x;
  for (int k = tid; k < NBD + NBS; k += PT) sh[k] = 0;
  __syncthreads();
  int C = (E + NWG - 1) / NWG;
  int e0 = w * C, e1 = min(E, e0 + C);
  for (int e = e0 + tid; e < e1; e += PT) {
    atomicAdd(&hD[dst[e] >> BSH], 1);
    atomicAdd(&hS[src[e] >> BSHS], 1);
  }
  __syncthreads();
  for (int b = tid; b < NBD; b += PT) cntAll[b * NWG + w] = hD[b];
  for (int b = tid; b < NBS; b += PT) cntAll[(NBD + b) * NWG + w] = hS[b];
}

// ---------------- flat exclusive scan (in place), 1024-thread blocks ----------------
__global__ void k_scanA(int* __restrict__ data, int* __restrict__ partials, int TOT) {
  __shared__ int lds[1024];
  int tid = threadIdx.x;
  int g = blockIdx.x * 1024 + tid;
  int v = (g < TOT) ? data[g] : 0;
  lds[tid] = v; __syncthreads();
  for (int o = 1; o < 1024; o <<= 1) {
    int t = (tid >= o) ? lds[tid - o] : 0;
    __syncthreads();
    lds[tid] += t;
    __syncthreads();
  }
  if (g < TOT) data[g] = lds[tid] - v;
  if (tid == 1023) partials[blockIdx.x] = lds[1023];
}

__global__ void k_scanB(int* partials, int nb, unsigned* maxbits) {
  __shared__ int lds[1024];
  int tid = threadIdx.x;
  if (tid == 0) *maxbits = 0u;
  int v = (tid < nb) ? partials[tid] : 0;
  lds[tid] = v; __syncthreads();
  for (int o = 1; o < 1024; o <<= 1) {
    int t = (tid >= o) ? lds[tid - o] : 0;
    __syncthreads();
    lds[tid] += t;
    __syncthreads();
  }
  if (tid < nb) partials[tid] = lds[tid] - v;
}

__global__ void k_scanC(int* __restrict__ data, const int* __restrict__ partials, int TOT) {
  int g = blockIdx.x * 1024 + threadIdx.x;
  if (g < TOT) data[g] += partials[g >> 10];
}

// ------- P3: partition; dst side LDS-sorted per sub-chunk for dense line fills -------
__global__ void __launch_bounds__(PT) k_part(
    const int* __restrict__ src, const int* __restrict__ dst,
    const float* __restrict__ ew, const int* __restrict__ baseAll,
    int2* __restrict__ gD, unsigned* __restrict__ gS,
    int NBD, int NBS, int E) {
  __shared__ int2 seg[SUBC];              // 48 KB sorted staging
  __shared__ unsigned short bkt[SUBC];    // 12 KB bucket tag per sorted slot
  __shared__ int cD[784];                 // this block's global dst cursors
  __shared__ int cS[104];                 // src cursors (unstaged path)
  __shared__ int excl[784];               // per-subchunk exclusive offsets
  __shared__ int lcur[784];               // hist, then scatter cursor
  __shared__ int scanT[1024];
  int tid = threadIdx.x, w = blockIdx.x;
  for (int b = tid; b < NBD; b += PT) cD[b] = baseAll[b * NWG + w];
  for (int b = tid; b < NBS; b += PT) cS[b] = baseAll[(NBD + b) * NWG + w] - E;
  __syncthreads();
  int C = (E + NWG - 1) / NWG;
  int e0 = w * C, e1 = min(E, e0 + C);
  for (int c0 = e0; c0 < e1; c0 += SUBC) {
    int cnt = min(SUBC, e1 - c0);
    for (int b = tid; b < NBD; b += PT) lcur[b] = 0;
    __syncthreads();
    // pass1: dst histogram + src-side scatter (unchanged behavior)
    for (int k = tid; k < cnt; k += PT) {
      int e = c0 + k;
      int s = src[e], d = dst[e];
      atomicAdd(&lcur[d >> BSH], 1);
      int pS = atomicAdd(&cS[s >> BSHS], 1);
      gS[pS] = ((unsigned)(s & (BSZS - 1)) << 16) | (unsigned)__half_as_ushort(__float2half(ew[e]));
    }
    __syncthreads();
    // scan hist -> exclusive offsets
    int v = (tid < NBD) ? lcur[tid] : 0;
    scanT[tid] = v;
    __syncthreads();
    for (int o = 1; o < 1024; o <<= 1) {
      int t = (tid >= o) ? scanT[tid - o] : 0;
      __syncthreads();
      scanT[tid] += t;
      __syncthreads();
    }
    if (tid < NBD) { excl[tid] = scanT[tid] - v; lcur[tid] = scanT[tid] - v; }
    __syncthreads();
    // pass2: scatter edges into bucket-sorted LDS order
    for (int k = tid; k < cnt; k += PT) {
      int e = c0 + k;
      int s = src[e], d = dst[e];
      int b = d >> BSH;
      int slot = atomicAdd(&lcur[b], 1);
      seg[slot] = make_int2(s | ((d & (BSZ - 1)) << 24), __float_as_int(ew[e]));
      bkt[slot] = (unsigned short)b;
    }
    __syncthreads();
    // pass3: dense write-out; consecutive k in a bucket -> consecutive gD addresses
    for (int k = tid; k < cnt; k += PT) {
      int b = bkt[k];
      gD[cD[b] + (k - excl[b])] = seg[k];
    }
    __syncthreads();
    // advance global cursors by this sub-chunk's per-bucket counts
    for (int b = tid; b < NBD; b += PT) cD[b] += lcur[b] - excl[b];
    __syncthreads();
  }
}

// ------- P4a: per-dst-bucket local counting sort -> CSR (in place) + off + dinv -------
__global__ void k_csr(int2* __restrict__ gD, const int* __restrict__ baseAll,
                      int* __restrict__ off, float* __restrict__ dinv,
                      int NBD, int N, int E) {
  __shared__ int2 seg[SEGCAP];
  __shared__ int hist[BSZ];
  __shared__ int curs[BSZ];
  __shared__ float degf[BSZ];
  int tid = threadIdx.x, b = blockIdx.x;
  int bstart = baseAll[b * NWG];
  int bend = (b + 1 < NBD) ? baseAll[(b + 1) * NWG] : E;
  int cnt = bend - bstart;
  for (int k = tid; k < cnt; k += 256) seg[k] = gD[bstart + k];
  if (tid < BSZ) { hist[tid] = 0; degf[tid] = 0.f; }
  __syncthreads();
  for (int k = tid; k < cnt; k += 256) {
    int dl = seg[k].x >> 24;
    atomicAdd(&hist[dl], 1);
    atomicAdd(&degf[dl], __int_as_float(seg[k].y));
  }
  __syncthreads();
  int v = (tid < BSZ) ? hist[tid] : 0;
  for (int o = 1; o < BSZ; o <<= 1) {
    int t = (tid < BSZ && tid >= o) ? hist[tid - o] : 0;
    __syncthreads();
    if (tid < BSZ) hist[tid] += t;
    __syncthreads();
  }
  if (tid < BSZ) {
    int excl = hist[tid] - v;
    curs[tid] = excl;
    int node = b * BSZ + tid;
    if (node < N) {
      off[node] = bstart + excl;
      dinv[node] = rsqrtf(1.0f + degf[tid]);
    }
  }
  if (b == NBD - 1 && tid == 0) off[N] = E;
  __syncthreads();
  for (int k = tid; k < cnt; k += 256) {
    int2 ev = seg[k];
    int dl = ev.x >> 24;
    int slot = atomicAdd(&curs[dl], 1);
    gD[bstart + slot] = make_int2(ev.x & 0xFFFFFF, ev.y);
  }
}

// ------- P4b: per-src-bucket (1024 nodes) weighted out-degree (dw) + global max -------
__global__ void k_dw(const unsigned* __restrict__ gS, const int* __restrict__ baseAll,
                     float* __restrict__ dw, unsigned* maxbits,
                     int NBD, int NBS, int N, int E) {
  __shared__ float acc[BSZS];
  int tid = threadIdx.x, b = blockIdx.x;
  int bstart = baseAll[(NBD + b) * NWG] - E;
  int bend = (b + 1 < NBS) ? baseAll[(NBD + b + 1) * NWG] - E : E;
  acc[tid] = 0.f;
  __syncthreads();
  for (int k = bstart + tid; k < bend; k += BSZS) {
    unsigned p = gS[k];
    atomicAdd(&acc[p >> 16], __half2float(__ushort_as_half((unsigned short)(p & 0xFFFFu))));
  }
  __syncthreads();
  float m = 0.f;
  int node = b * BSZS + tid;
  if (node < N) { dw[node] = acc[tid]; m = acc[tid]; }
  for (int mm = 32; mm; mm >>= 1) m = fmaxf(m, __shfl_xor(m, mm, 64));
  if ((tid & 63) == 0) atomicMax(maxbits, __float_as_uint(m));
}

// ------- g0 = dinv[i] * (x @ W1) row, MFMA 16x16x32 bf16, stored fp8 e4m3 -------
// A: row=l&15, k=(l>>4)*8+i ; B: col=l&15, k=(l>>4)*8+i ; D: col=l&15, row=(l>>4)*4+reg
__global__ void k_gemm1(const float* __restrict__ x, const float* __restrict__ W1,
                        const float* __restrict__ dinv, unsigned char* __restrict__ g0, int N) {
  int lane = threadIdx.x & 63;
  int wid = (blockIdx.x * blockDim.x + threadIdx.x) >> 6;
  int nw = (gridDim.x * blockDim.x) >> 6;
  int l16 = lane & 15, lh = lane >> 4;
  bf16x8 bfrag[4][4];
#pragma unroll
  for (int cb = 0; cb < 4; ++cb)
#pragma unroll
    for (int kf = 0; kf < 4; ++kf)
#pragma unroll
      for (int i = 0; i < 8; ++i) {
        int k = kf * 32 + lh * 8 + i;
        bfrag[cb][kf][i] = f32_bf16(W1[k * F_HID + cb * 16 + l16]);
      }
  int ntiles = (N + 15) >> 4;
  for (int t = wid; t < ntiles; t += nw) {
    int rowbase = t << 4;
    int row = min(rowbase + l16, N - 1);
    bf16x8 afrag[4];
#pragma unroll
    for (int kf = 0; kf < 4; ++kf) {
      const f32x4* xp = (const f32x4*)(x + (size_t)row * F_IN + kf * 32 + lh * 8);
      f32x4 v0 = xp[0], v1 = xp[1];
#pragma unroll
      for (int i = 0; i < 4; ++i) afrag[kf][i] = f32_bf16(v0[i]);
#pragma unroll
      for (int i = 0; i < 4; ++i) afrag[kf][4 + i] = f32_bf16(v1[i]);
    }
    f32x4 acc[4] = {{0.f,0.f,0.f,0.f},{0.f,0.f,0.f,0.f},{0.f,0.f,0.f,0.f},{0.f,0.f,0.f,0.f}};
#pragma unroll
    for (int cb = 0; cb < 4; ++cb)
#pragma unroll
      for (int kf = 0; kf < 4; ++kf)
        acc[cb] = __builtin_amdgcn_mfma_f32_16x16x32_bf16(afrag[kf], bfrag[cb][kf], acc[cb], 0, 0, 0);
    if (rowbase + 16 <= N) {
      f32x4 dv = *(const f32x4*)(dinv + rowbase + lh * 4);
#pragma unroll
      for (int cb = 0; cb < 4; ++cb)
#pragma unroll
        for (int r = 0; r < 4; ++r) {
          int rr = rowbase + lh * 4 + r;
          g0[(size_t)rr * F_HID + cb * 16 + l16] = f32_to_fp8(acc[cb][r] * dv[r]);
        }
    } else {
#pragma unroll
      for (int cb = 0; cb < 4; ++cb)
#pragma unroll
        for (int r = 0; r < 4; ++r) {
          int rr = rowbase + lh * 4 + r;
          if (rr < N)
            g0[(size_t)rr * F_HID + cb * 16 + l16] = f32_to_fp8(acc[cb][r] * dinv[rr]);
        }
    }
  }
}

// ------- layer-1 agg: wave per node; 8 edge-slots x 8 lanes x 8 features; pk-fma -------
__global__ void k_agg1(const unsigned char* __restrict__ g0, const float* __restrict__ dinv,
                       const int* __restrict__ off, const int2* __restrict__ csr,
                       const float* __restrict__ b1, const float* __restrict__ W2,
                       float* __restrict__ u, int N) {
  int lane = threadIdx.x & 63;
  int grp = lane >> 3;        // edge slot 0..7
  int l8  = lane & 7;         // feature octet 0..7
  int i = (blockIdx.x * blockDim.x + threadIdx.x) >> 6;
  if (i >= N) return;
  const uint2* g0v = (const uint2*)g0;
  f32x2 acc2[4] = {{0.f,0.f},{0.f,0.f},{0.f,0.f},{0.f,0.f}};
  if (grp == 0) {             // self contribution once (group 0)
    uint2 rv = g0v[(size_t)i * 8 + l8];
    acc2[0] += __builtin_amdgcn_cvt_pk_f32_fp8(rv.x, false);
    acc2[1] += __builtin_amdgcn_cvt_pk_f32_fp8(rv.x, true);
    acc2[2] += __builtin_amdgcn_cvt_pk_f32_fp8(rv.y, false);
    acc2[3] += __builtin_amdgcn_cvt_pk_f32_fp8(rv.y, true);
  }
  int p0 = off[i], p1 = off[i + 1];
  for (int p = p0; p < p1; p += 64) {
    int m = min(p1 - p, 64);
    int2 ed = make_int2(0, 0);
    if (lane < m) ed = nt_i2(&csr[p + lane]);   // stream CSR: evict-first in L2
#pragma unroll
    for (int jj = 0; jj < 8; ++jj) {
      int j = jj * 8 + grp;
      int s = __shfl(ed.x, j, 64);
      float w = __int_as_float(__shfl(ed.y, j, 64));
      if (j < m) {
        uint2 rv = g0v[(size_t)s * 8 + l8];
        f32x2 w2; w2.x = w; w2.y = w;
        acc2[0] = __builtin_elementwise_fma(__builtin_amdgcn_cvt_pk_f32_fp8(rv.x, false), w2, acc2[0]);
        acc2[1] = __builtin_elementwise_fma(__builtin_amdgcn_cvt_pk_f32_fp8(rv.x, true),  w2, acc2[1]);
        acc2[2] = __builtin_elementwise_fma(__builtin_amdgcn_cvt_pk_f32_fp8(rv.y, false), w2, acc2[2]);
        acc2[3] = __builtin_elementwise_fma(__builtin_amdgcn_cvt_pk_f32_fp8(rv.y, true),  w2, acc2[3]);
      }
    }
  }
  float acc[8] = {acc2[0].x, acc2[0].y, acc2[1].x, acc2[1].y,
                  acc2[2].x, acc2[2].y, acc2[3].x, acc2[3].y};
#pragma unroll
  for (int k = 0; k < 8; ++k) {
    acc[k] += __shfl_xor(acc[k], 8, 64);
    acc[k] += __shfl_xor(acc[k], 16, 64);
    acc[k] += __shfl_xor(acc[k], 32, 64);
  }
  float di = dinv[i];
  float pdt = 0.f;
#pragma unroll
  for (int k = 0; k < 8; ++k) {
    int f = l8 * 8 + k;
    float h = fmaxf(di * acc[k] + b1[f], 0.f);
    pdt = fmaf(h, W2[f], pdt);
  }
  pdt += __shfl_xor(pdt, 1, 64);
  pdt += __shfl_xor(pdt, 2, 64);
  pdt += __shfl_xor(pdt, 4, 64);
  if (lane == 0) u[i] = di * pdt;
}

// ------- layer-2 agg + final: 2 nodes per wave (32-lane groups) -------
__global__ void k_agg2_final(const float* __restrict__ u, const float* __restrict__ dinv,
                             const int* __restrict__ off, const int2* __restrict__ csr,
                             const float* __restrict__ b2, const float* __restrict__ dw,
                             const unsigned* __restrict__ maxbits,
                             float* __restrict__ out, int N) {
  int lane32 = threadIdx.x & 31;
  int i = blockIdx.x * 8 + (threadIdx.x >> 5);   // 8 nodes per 256-thread block
  if (i >= N) return;
  float acc = (lane32 == 0) ? u[i] : 0.f;        // self (u_i)
  int p0 = off[i], p1 = off[i + 1];
  for (int p = p0 + lane32; p < p1; p += 32) {
    int2 ed = nt_i2(&csr[p]);                    // stream CSR: protect u in L2
    acc = fmaf(__int_as_float(ed.y), u[ed.x], acc);
  }
  for (int mm = 16; mm; mm >>= 1) acc += __shfl_xor(acc, mm, 64);
  if (lane32 == 0) {
    float md = __uint_as_float(*maxbits);
    float z = dinv[i] * acc + b2[0];
    float sc = 1.0f / (1.0f + expf(-z));
    out[i] = sc * (1.0f + dw[i] / md);
  }
}

extern "C" void kernel_launch(void* const* d_in, const int* in_sizes, int n_in,
                              void* d_out, int out_size, void* d_ws, size_t ws_size,
                              hipStream_t stream) {
  const float* x  = (const float*)d_in[0];
  const int*   ei = (const int*)d_in[1];
  const float* ew = (const float*)d_in[2];
  const float* W1 = (const float*)d_in[3];
  const float* b1 = (const float*)d_in[4];
  const float* W2 = (const float*)d_in[5];
  const float* b2 = (const float*)d_in[6];
  float* out = (float*)d_out;

  int N = out_size;      // 100000
  int E = in_sizes[2];   // 3200000
  const int* src = ei;
  const int* dst = ei + E;

  int NBD = (N + BSZ - 1) >> BSH;       // 782
  int NBS = (N + BSZS - 1) >> BSHS;     // 98
  int TOT = (NBD + NBS) * NWG;          // 225280
  int SB = (TOT + 1023) >> 10;          // 220
  size_t shmem = (size_t)(NBD + NBS) * sizeof(int);

  char* w8 = (char*)d_ws;
  int2*     gD      = (int2*)w8;                         // E int2  (becomes CSR in place)
  unsigned* gS      = (unsigned*)(gD + E);               // E u32
  int*      cntAll  = (int*)(gS + E);                    // TOT i  (scanned in place)
  int*      partials= cntAll + TOT;                      // 1024 i
  int*      off     = partials + 1024;                   // N+1 i
  float*    dinv    = (float*)(off + N + 1);             // N f
  float*    dw      = dinv + N;                          // N f
  float*    u       = dw + N;                            // N f
  unsigned* maxbits = (unsigned*)(u + N);                // 1 u
  unsigned char* g0 = (unsigned char*)(maxbits + 2);     // N*64 fp8

  k_count<<<NWG, PT, shmem, stream>>>(src, dst, cntAll, NBD, NBS, E);
  k_scanA<<<SB, 1024, 0, stream>>>(cntAll, partials, TOT);
  k_scanB<<<1, 1024, 0, stream>>>(partials, SB, maxbits);
  k_scanC<<<SB, 1024, 0, stream>>>(cntAll, partials, TOT);
  k_part<<<NWG, PT, 0, stream>>>(src, dst, ew, cntAll, gD, gS, NBD, NBS, E);
  k_csr<<<NBD, 256, 0, stream>>>(gD, cntAll, off, dinv, NBD, N, E);
  k_dw<<<NBS, BSZS, 0, stream>>>(gS, cntAll, dw, maxbits, NBD, NBS, N, E);
  k_gemm1<<<256, 256, 0, stream>>>(x, W1, dinv, g0, N);
  k_agg1<<<(N * 64 + 255) / 256, 256, 0, stream>>>(g0, dinv, off, gD, b1, W2, u, N);
  k_agg2_final<<<(N + 7) / 8, 256, 0, stream>>>(u, dinv, off, gD, b2, dw, maxbits, out, N);
}

// Round 20
// 264.478 us; speedup vs baseline: 1.0549x; 1.0549x over previous
//
#include <hip/hip_runtime.h>
#include <hip/hip_fp16.h>
#include <math.h>

#define F_IN 128
#define F_HID 64
#define NWG 256      // partition chunks (= blocks of k_part)
#define PT 1024      // threads per partition block
#define BSH 7        // dst bucket shift (128 nodes per bucket)
#define BSZ 128
#define BSHS 10      // src bucket shift (1024 nodes per bucket)
#define BSZS 1024
#define SLAB_D 4608  // dst slab capacity (mean 4096, +8 sigma; proven r12)
#define SLAB_S 34816 // src slab capacity (mean 32653, +12 sigma)
#define SEGCAP 6144  // LDS staging for k_csr (>= SLAB_D)
#define SUBC 6144    // k_part sub-chunk (LDS-sorted before write-out)

typedef float f32x2 __attribute__((ext_vector_type(2)));
typedef float f32x4 __attribute__((ext_vector_type(4)));
typedef __bf16 bf16x8 __attribute__((ext_vector_type(8)));

// ---- fp8 e4m3 (OCP, gfx950 HW cvt) ----
__device__ __forceinline__ unsigned char f32_to_fp8(float v) {
  unsigned r = __builtin_amdgcn_cvt_pk_fp8_f32(v, v, 0, false);
  return (unsigned char)(r & 0xFFu);
}

// ---- f32 -> bf16 RTNE (bit-manip) ----
__device__ __forceinline__ __bf16 f32_bf16(float f) {
  unsigned u = __float_as_uint(f);
  unsigned r = (u + 0x7FFFu + ((u >> 16) & 1u)) >> 16;
  return __builtin_bit_cast(__bf16, (unsigned short)r);
}

// ------- init: slab cursors + maxbits -------
__global__ void k_init0(int* cursD, int* cursS, unsigned* maxbits, int NBD, int NBS) {
  int t = threadIdx.x;
  for (int b = t; b < NBD; b += 1024) cursD[b] = b * SLAB_D;
  for (int b = t; b < NBS; b += 1024) cursS[b] = b * SLAB_S;
  if (t == 0) *maxbits = 0u;
}

// ------- partition: per sub-chunk LDS sort + global slab reservation, dense writes -------
__global__ void __launch_bounds__(PT) k_part(
    const int* __restrict__ src, const int* __restrict__ dst,
    const float* __restrict__ ew, int* cursD_g, int* cursS_g,
    int2* __restrict__ gD, unsigned* __restrict__ gS,
    int NBD, int NBS, int E) {
  __shared__ int2 seg[SUBC];              // 48 KB sorted staging
  __shared__ unsigned short bkt[SUBC];    // 12 KB bucket tag per sorted slot
  __shared__ int lcur[784];               // hist -> LDS scatter cursor
  __shared__ int excl[784];               // per-subchunk exclusive offsets (LDS slots)
  __shared__ int gbase[784];              // reserved global window base per bucket
  __shared__ int scanT[1024];
  __shared__ int hS[104];                 // src hist
  __shared__ int baseS[104];              // reserved src window base
  __shared__ int lcurS[104];              // src scatter cursor
  int tid = threadIdx.x, w = blockIdx.x;
  int C = (E + NWG - 1) / NWG;
  int e0 = w * C, e1 = min(E, e0 + C);
  for (int c0 = e0; c0 < e1; c0 += SUBC) {
    int cnt = min(SUBC, e1 - c0);
    for (int b = tid; b < NBD; b += PT) lcur[b] = 0;
    if (tid < NBS) { hS[tid] = 0; lcurS[tid] = 0; }
    __syncthreads();
    // pass1: histograms (dst fine, src coarse)
    for (int k = tid; k < cnt; k += PT) {
      int e = c0 + k;
      atomicAdd(&lcur[dst[e] >> BSH], 1);
      atomicAdd(&hS[src[e] >> BSHS], 1);
    }
    __syncthreads();
    // reserve global windows (one atomic per non-empty bucket per sub-chunk)
    for (int b = tid; b < NBD; b += PT) {
      int c = lcur[b];
      gbase[b] = c ? atomicAdd(&cursD_g[b], c) : 0;
    }
    if (tid < NBS) {
      int c = hS[tid];
      baseS[tid] = c ? atomicAdd(&cursS_g[tid], c) : 0;
    }
    // scan dst hist -> LDS slot offsets
    int v = (tid < NBD) ? lcur[tid] : 0;
    scanT[tid] = v;
    __syncthreads();
    for (int o = 1; o < 1024; o <<= 1) {
      int t = (tid >= o) ? scanT[tid - o] : 0;
      __syncthreads();
      scanT[tid] += t;
      __syncthreads();
    }
    if (tid < NBD) { excl[tid] = scanT[tid] - v; lcur[tid] = scanT[tid] - v; }
    __syncthreads();
    // pass2: scatter dst edges into bucket-sorted LDS; src edges direct to window
    for (int k = tid; k < cnt; k += PT) {
      int e = c0 + k;
      int s = src[e], d = dst[e];
      float wv = ew[e];
      int b = d >> BSH;
      int slot = atomicAdd(&lcur[b], 1);
      seg[slot] = make_int2(s | ((d & (BSZ - 1)) << 24), __float_as_int(wv));
      bkt[slot] = (unsigned short)b;
      int bs = s >> BSHS;
      int slotS = atomicAdd(&lcurS[bs], 1);
      gS[baseS[bs] + slotS] = ((unsigned)(s & (BSZS - 1)) << 16)
                            | (unsigned)__half_as_ushort(__float2half(wv));
    }
    __syncthreads();
    // pass3: dense write-out to reserved windows
    for (int k = tid; k < cnt; k += PT) {
      int b = bkt[k];
      gD[gbase[b] + (k - excl[b])] = seg[k];
    }
    __syncthreads();
  }
}

// ------- per-dst-bucket local counting sort -> CSR (in place) + off/degN/dinv -------
__global__ void k_csr(int2* __restrict__ gD, const int* __restrict__ cursD_g,
                      int* __restrict__ off, int* __restrict__ degN,
                      float* __restrict__ dinv, int NBD, int N) {
  __shared__ int2 seg[SEGCAP];
  __shared__ int hist[BSZ];
  __shared__ int curs[BSZ];
  __shared__ float degf[BSZ];
  int tid = threadIdx.x, b = blockIdx.x;
  int bstart = b * SLAB_D;
  int bend = cursD_g[b];
  int cnt = bend - bstart;
  for (int k = tid; k < cnt; k += 256) seg[k] = gD[bstart + k];
  if (tid < BSZ) { hist[tid] = 0; degf[tid] = 0.f; }
  __syncthreads();
  for (int k = tid; k < cnt; k += 256) {
    int dl = (unsigned)seg[k].x >> 24;
    atomicAdd(&hist[dl], 1);
    atomicAdd(&degf[dl], __int_as_float(seg[k].y));
  }
  __syncthreads();
  int v = (tid < BSZ) ? hist[tid] : 0;
  for (int o = 1; o < BSZ; o <<= 1) {
    int t = (tid < BSZ && tid >= o) ? hist[tid - o] : 0;
    __syncthreads();
    if (tid < BSZ) hist[tid] += t;
    __syncthreads();
  }
  if (tid < BSZ) {
    int excl = hist[tid] - v;
    curs[tid] = excl;
    int node = b * BSZ + tid;
    if (node < N) {
      off[node] = bstart + excl;
      degN[node] = v;
      dinv[node] = rsqrtf(1.0f + degf[tid]);
    }
  }
  __syncthreads();
  for (int k = tid; k < cnt; k += 256) {
    int2 ev = seg[k];
    int dl = (unsigned)ev.x >> 24;
    int slot = atomicAdd(&curs[dl], 1);
    gD[bstart + slot] = make_int2(ev.x & 0xFFFFFF, ev.y);
  }
}

// ------- per-src-slab weighted out-degree (dw) + global max -------
__global__ void k_dw(const unsigned* __restrict__ gS, const int* __restrict__ cursS_g,
                     float* __restrict__ dw, unsigned* maxbits, int NBS, int N) {
  __shared__ float acc[BSZS];
  int tid = threadIdx.x, b = blockIdx.x;
  int bstart = b * SLAB_S;
  int bend = cursS_g[b];
  acc[tid] = 0.f;
  __syncthreads();
  for (int k = bstart + tid; k < bend; k += BSZS) {
    unsigned p = gS[k];
    atomicAdd(&acc[p >> 16], __half2float(__ushort_as_half((unsigned short)(p & 0xFFFFu))));
  }
  __syncthreads();
  float m = 0.f;
  int node = b * BSZS + tid;
  if (node < N) { dw[node] = acc[tid]; m = acc[tid]; }
  for (int mm = 32; mm; mm >>= 1) m = fmaxf(m, __shfl_xor(m, mm, 64));
  if ((tid & 63) == 0) atomicMax(maxbits, __float_as_uint(m));
}

// ------- g0 = dinv[i] * (x @ W1) row, MFMA 16x16x32 bf16, stored fp8 e4m3 -------
// A: row=l&15, k=(l>>4)*8+i ; B: col=l&15, k=(l>>4)*8+i ; D: col=l&15, row=(l>>4)*4+reg
__global__ void k_gemm1(const float* __restrict__ x, const float* __restrict__ W1,
                        const float* __restrict__ dinv, unsigned char* __restrict__ g0, int N) {
  int lane = threadIdx.x & 63;
  int wid = (blockIdx.x * blockDim.x + threadIdx.x) >> 6;
  int nw = (gridDim.x * blockDim.x) >> 6;
  int l16 = lane & 15, lh = lane >> 4;
  bf16x8 bfrag[4][4];
#pragma unroll
  for (int cb = 0; cb < 4; ++cb)
#pragma unroll
    for (int kf = 0; kf < 4; ++kf)
#pragma unroll
      for (int i = 0; i < 8; ++i) {
        int k = kf * 32 + lh * 8 + i;
        bfrag[cb][kf][i] = f32_bf16(W1[k * F_HID + cb * 16 + l16]);
      }
  int ntiles = (N + 15) >> 4;
  for (int t = wid; t < ntiles; t += nw) {
    int rowbase = t << 4;
    int row = min(rowbase + l16, N - 1);
    bf16x8 afrag[4];
#pragma unroll
    for (int kf = 0; kf < 4; ++kf) {
      const f32x4* xp = (const f32x4*)(x + (size_t)row * F_IN + kf * 32 + lh * 8);
      f32x4 v0 = xp[0], v1 = xp[1];
#pragma unroll
      for (int i = 0; i < 4; ++i) afrag[kf][i] = f32_bf16(v0[i]);
#pragma unroll
      for (int i = 0; i < 4; ++i) afrag[kf][4 + i] = f32_bf16(v1[i]);
    }
    f32x4 acc[4] = {{0.f,0.f,0.f,0.f},{0.f,0.f,0.f,0.f},{0.f,0.f,0.f,0.f},{0.f,0.f,0.f,0.f}};
#pragma unroll
    for (int cb = 0; cb < 4; ++cb)
#pragma unroll
      for (int kf = 0; kf < 4; ++kf)
        acc[cb] = __builtin_amdgcn_mfma_f32_16x16x32_bf16(afrag[kf], bfrag[cb][kf], acc[cb], 0, 0, 0);
    if (rowbase + 16 <= N) {
      f32x4 dv = *(const f32x4*)(dinv + rowbase + lh * 4);
#pragma unroll
      for (int cb = 0; cb < 4; ++cb)
#pragma unroll
        for (int r = 0; r < 4; ++r) {
          int rr = rowbase + lh * 4 + r;
          g0[(size_t)rr * F_HID + cb * 16 + l16] = f32_to_fp8(acc[cb][r] * dv[r]);
        }
    } else {
#pragma unroll
      for (int cb = 0; cb < 4; ++cb)
#pragma unroll
        for (int r = 0; r < 4; ++r) {
          int rr = rowbase + lh * 4 + r;
          if (rr < N)
            g0[(size_t)rr * F_HID + cb * 16 + l16] = f32_to_fp8(acc[cb][r] * dinv[rr]);
        }
    }
  }
}

// ------- layer-1 agg: wave per node; 8 edge-slots x 8 lanes x 8 features; pk-fma -------
__global__ void k_agg1(const unsigned char* __restrict__ g0, const float* __restrict__ dinv,
                       const int* __restrict__ off, const int* __restrict__ degN,
                       const int2* __restrict__ csr,
                       const float* __restrict__ b1, const float* __restrict__ W2,
                       float* __restrict__ u, int N) {
  int lane = threadIdx.x & 63;
  int grp = lane >> 3;        // edge slot 0..7
  int l8  = lane & 7;         // feature octet 0..7
  int i = (blockIdx.x * blockDim.x + threadIdx.x) >> 6;
  if (i >= N) return;
  const uint2* g0v = (const uint2*)g0;
  f32x2 acc2[4] = {{0.f,0.f},{0.f,0.f},{0.f,0.f},{0.f,0.f}};
  if (grp == 0) {             // self contribution once (group 0)
    uint2 rv = g0v[(size_t)i * 8 + l8];
    acc2[0] += __builtin_amdgcn_cvt_pk_f32_fp8(rv.x, false);
    acc2[1] += __builtin_amdgcn_cvt_pk_f32_fp8(rv.x, true);
    acc2[2] += __builtin_amdgcn_cvt_pk_f32_fp8(rv.y, false);
    acc2[3] += __builtin_amdgcn_cvt_pk_f32_fp8(rv.y, true);
  }
  int p0 = off[i], p1 = p0 + degN[i];
  for (int p = p0; p < p1; p += 64) {
    int m = min(p1 - p, 64);
    int2 ed = make_int2(0, 0);
    if (lane < m) ed = csr[p + lane];
#pragma unroll
    for (int jj = 0; jj < 8; ++jj) {
      int j = jj * 8 + grp;
      int s = __shfl(ed.x, j, 64);
      float w = __int_as_float(__shfl(ed.y, j, 64));
      if (j < m) {
        uint2 rv = g0v[(size_t)s * 8 + l8];
        f32x2 w2; w2.x = w; w2.y = w;
        acc2[0] = __builtin_elementwise_fma(__builtin_amdgcn_cvt_pk_f32_fp8(rv.x, false), w2, acc2[0]);
        acc2[1] = __builtin_elementwise_fma(__builtin_amdgcn_cvt_pk_f32_fp8(rv.x, true),  w2, acc2[1]);
        acc2[2] = __builtin_elementwise_fma(__builtin_amdgcn_cvt_pk_f32_fp8(rv.y, false), w2, acc2[2]);
        acc2[3] = __builtin_elementwise_fma(__builtin_amdgcn_cvt_pk_f32_fp8(rv.y, true),  w2, acc2[3]);
      }
    }
  }
  float acc[8] = {acc2[0].x, acc2[0].y, acc2[1].x, acc2[1].y,
                  acc2[2].x, acc2[2].y, acc2[3].x, acc2[3].y};
#pragma unroll
  for (int k = 0; k < 8; ++k) {
    acc[k] += __shfl_xor(acc[k], 8, 64);
    acc[k] += __shfl_xor(acc[k], 16, 64);
    acc[k] += __shfl_xor(acc[k], 32, 64);
  }
  float di = dinv[i];
  float pdt = 0.f;
#pragma unroll
  for (int k = 0; k < 8; ++k) {
    int f = l8 * 8 + k;
    float h = fmaxf(di * acc[k] + b1[f], 0.f);
    pdt = fmaf(h, W2[f], pdt);
  }
  pdt += __shfl_xor(pdt, 1, 64);
  pdt += __shfl_xor(pdt, 2, 64);
  pdt += __shfl_xor(pdt, 4, 64);
  if (lane == 0) u[i] = di * pdt;
}

// ------- layer-2 agg + final: 2 nodes per wave (32-lane groups) -------
__global__ void k_agg2_final(const float* __restrict__ u, const float* __restrict__ dinv,
                             const int* __restrict__ off, const int* __restrict__ degN,
                             const int2* __restrict__ csr,
                             const float* __restrict__ b2, const float* __restrict__ dw,
                             const unsigned* __restrict__ maxbits,
                             float* __restrict__ out, int N) {
  int lane32 = threadIdx.x & 31;
  int i = blockIdx.x * 8 + (threadIdx.x >> 5);   // 8 nodes per 256-thread block
  if (i >= N) return;
  float acc = (lane32 == 0) ? u[i] : 0.f;        // self (u_i)
  int p0 = off[i], p1 = p0 + degN[i];
  for (int p = p0 + lane32; p < p1; p += 32) {
    int2 ed = csr[p];
    acc = fmaf(__int_as_float(ed.y), u[ed.x], acc);
  }
  for (int mm = 16; mm; mm >>= 1) acc += __shfl_xor(acc, mm, 64);
  if (lane32 == 0) {
    float md = __uint_as_float(*maxbits);
    float z = dinv[i] * acc + b2[0];
    float sc = 1.0f / (1.0f + expf(-z));
    out[i] = sc * (1.0f + dw[i] / md);
  }
}

extern "C" void kernel_launch(void* const* d_in, const int* in_sizes, int n_in,
                              void* d_out, int out_size, void* d_ws, size_t ws_size,
                              hipStream_t stream) {
  const float* x  = (const float*)d_in[0];
  const int*   ei = (const int*)d_in[1];
  const float* ew = (const float*)d_in[2];
  const float* W1 = (const float*)d_in[3];
  const float* b1 = (const float*)d_in[4];
  const float* W2 = (const float*)d_in[5];
  const float* b2 = (const float*)d_in[6];
  float* out = (float*)d_out;

  int N = out_size;      // 100000
  int E = in_sizes[2];   // 3200000
  const int* src = ei;
  const int* dst = ei + E;

  int NBD = (N + BSZ - 1) >> BSH;       // 782
  int NBS = (N + BSZS - 1) >> BSHS;     // 98
  size_t slabD = (size_t)NBD * SLAB_D;  // 3.60M entries
  size_t slabS = (size_t)NBS * SLAB_S;  // 3.41M entries

  char* w8 = (char*)d_ws;
  int2*     gD    = (int2*)w8;                        // slabD int2 (28.8 MB; becomes CSR)
  unsigned* gS    = (unsigned*)(gD + slabD);          // slabS u32 (13.6 MB)
  unsigned char* g0 = (unsigned char*)(gS + slabS);   // N*64 fp8 (6.4 MB)
  int*      cursD = (int*)(g0 + (size_t)N * F_HID);   // NBD
  int*      cursS = cursD + NBD;                      // NBS
  int*      off   = cursS + NBS;                      // N
  int*      degN  = off + N;                          // N
  float*    dinv  = (float*)(degN + N);               // N
  float*    dw    = dinv + N;                         // N
  float*    u     = dw + N;                           // N
  unsigned* maxbits = (unsigned*)(u + N);             // 1

  k_init0<<<1, 1024, 0, stream>>>(cursD, cursS, maxbits, NBD, NBS);
  k_part<<<NWG, PT, 0, stream>>>(src, dst, ew, cursD, cursS, gD, gS, NBD, NBS, E);
  k_csr<<<NBD, 256, 0, stream>>>(gD, cursD, off, degN, dinv, NBD, N);
  k_dw<<<NBS, BSZS, 0, stream>>>(gS, cursS, dw, maxbits, NBS, N);
  k_gemm1<<<256, 256, 0, stream>>>(x, W1, dinv, g0, N);
  k_agg1<<<(N * 64 + 255) / 256, 256, 0, stream>>>(g0, dinv, off, degN, gD, b1, W2, u, N);
  k_agg2_final<<<(N + 7) / 8, 256, 0, stream>>>(u, dinv, off, degN, gD, b2, dw, maxbits, out, N);
}

// Round 21
// 259.896 us; speedup vs baseline: 1.0735x; 1.0176x over previous
//
#include <hip/hip_runtime.h>
#include <hip/hip_fp16.h>
#include <math.h>

#define F_IN 128
#define F_HID 64
#define NWG 512      // partition chunks (one sub-chunk per block; 2 blocks/CU)
#define PT 1024      // threads per partition block
#define BSH 7        // dst bucket shift (128 nodes per bucket)
#define BSZ 128
#define BSHS 10      // src bucket shift (1024 nodes per bucket)
#define BSZS 1024
#define SLAB_D 4608  // dst slab capacity (mean 4096, +8 sigma; proven r12/r20)
#define SLAB_S 34816 // src slab capacity (mean 32653, +12 sigma)
#define SEGCAP 6144  // LDS staging for k_csr (>= SLAB_D)
#define SUBC 6272    // k_part sub-chunk capacity (>= ceil(E/NWG) = 6250)

typedef float f32x2 __attribute__((ext_vector_type(2)));
typedef float f32x4 __attribute__((ext_vector_type(4)));
typedef __bf16 bf16x8 __attribute__((ext_vector_type(8)));

// ---- fp8 e4m3 (OCP, gfx950 HW cvt) ----
__device__ __forceinline__ unsigned char f32_to_fp8(float v) {
  unsigned r = __builtin_amdgcn_cvt_pk_fp8_f32(v, v, 0, false);
  return (unsigned char)(r & 0xFFu);
}

// ---- f32 -> bf16 RTNE (bit-manip) ----
__device__ __forceinline__ __bf16 f32_bf16(float f) {
  unsigned u = __float_as_uint(f);
  unsigned r = (u + 0x7FFFu + ((u >> 16) & 1u)) >> 16;
  return __builtin_bit_cast(__bf16, (unsigned short)r);
}

// ------- init: slab cursors + maxbits -------
__global__ void k_init0(int* cursD, int* cursS, unsigned* maxbits, int NBD, int NBS) {
  int t = threadIdx.x;
  for (int b = t; b < NBD; b += 1024) cursD[b] = b * SLAB_D;
  for (int b = t; b < NBS; b += 1024) cursS[b] = b * SLAB_S;
  if (t == 0) *maxbits = 0u;
}

// ------- partition: per sub-chunk LDS sort + global slab reservation, dense writes -------
__global__ void __launch_bounds__(PT) k_part(
    const int* __restrict__ src, const int* __restrict__ dst,
    const float* __restrict__ ew, int* cursD_g, int* cursS_g,
    int2* __restrict__ gD, unsigned* __restrict__ gS,
    int NBD, int NBS, int E) {
  __shared__ int2 seg[SUBC];              // 50 KB sorted staging
  __shared__ unsigned short bkt[SUBC];    // 12.5 KB bucket tag per sorted slot
  __shared__ int lcur[784];               // hist -> LDS scatter cursor
  __shared__ int excl[784];               // per-subchunk exclusive offsets (LDS slots)
  __shared__ int gbase[784];              // reserved global window base per bucket
  __shared__ int scanT[1024];
  __shared__ int hS[104];                 // src hist
  __shared__ int baseS[104];              // reserved src window base
  __shared__ int lcurS[104];              // src scatter cursor
  int tid = threadIdx.x, w = blockIdx.x;
  int C = (E + NWG - 1) / NWG;
  int e0 = w * C, e1 = min(E, e0 + C);
  for (int c0 = e0; c0 < e1; c0 += SUBC) {
    int cnt = min(SUBC, e1 - c0);
    for (int b = tid; b < NBD; b += PT) lcur[b] = 0;
    if (tid < NBS) { hS[tid] = 0; lcurS[tid] = 0; }
    __syncthreads();
    // pass1: histograms (dst fine, src coarse)
    for (int k = tid; k < cnt; k += PT) {
      int e = c0 + k;
      atomicAdd(&lcur[dst[e] >> BSH], 1);
      atomicAdd(&hS[src[e] >> BSHS], 1);
    }
    __syncthreads();
    // reserve global windows (one atomic per non-empty bucket per sub-chunk)
    for (int b = tid; b < NBD; b += PT) {
      int c = lcur[b];
      gbase[b] = c ? atomicAdd(&cursD_g[b], c) : 0;
    }
    if (tid < NBS) {
      int c = hS[tid];
      baseS[tid] = c ? atomicAdd(&cursS_g[tid], c) : 0;
    }
    // scan dst hist -> LDS slot offsets
    int v = (tid < NBD) ? lcur[tid] : 0;
    scanT[tid] = v;
    __syncthreads();
    for (int o = 1; o < 1024; o <<= 1) {
      int t = (tid >= o) ? scanT[tid - o] : 0;
      __syncthreads();
      scanT[tid] += t;
      __syncthreads();
    }
    if (tid < NBD) { excl[tid] = scanT[tid] - v; lcur[tid] = scanT[tid] - v; }
    __syncthreads();
    // pass2: scatter dst edges into bucket-sorted LDS; src edges direct to window
    for (int k = tid; k < cnt; k += PT) {
      int e = c0 + k;
      int s = src[e], d = dst[e];
      float wv = ew[e];
      int b = d >> BSH;
      int slot = atomicAdd(&lcur[b], 1);
      seg[slot] = make_int2(s | ((d & (BSZ - 1)) << 24), __float_as_int(wv));
      bkt[slot] = (unsigned short)b;
      int bs = s >> BSHS;
      int slotS = atomicAdd(&lcurS[bs], 1);
      gS[baseS[bs] + slotS] = ((unsigned)(s & (BSZS - 1)) << 16)
                            | (unsigned)__half_as_ushort(__float2half(wv));
    }
    __syncthreads();
    // pass3: dense write-out to reserved windows
    for (int k = tid; k < cnt; k += PT) {
      int b = bkt[k];
      gD[gbase[b] + (k - excl[b])] = seg[k];
    }
    __syncthreads();
  }
}

// ------- per-dst-bucket local counting sort -> CSR (in place) + off/degN/dinv -------
__global__ void k_csr(int2* __restrict__ gD, const int* __restrict__ cursD_g,
                      int* __restrict__ off, int* __restrict__ degN,
                      float* __restrict__ dinv, int NBD, int N) {
  __shared__ int2 seg[SEGCAP];
  __shared__ int hist[BSZ];
  __shared__ int curs[BSZ];
  __shared__ float degf[BSZ];
  int tid = threadIdx.x, b = blockIdx.x;
  int bstart = b * SLAB_D;
  int bend = cursD_g[b];
  int cnt = bend - bstart;
  for (int k = tid; k < cnt; k += 256) seg[k] = gD[bstart + k];
  if (tid < BSZ) { hist[tid] = 0; degf[tid] = 0.f; }
  __syncthreads();
  for (int k = tid; k < cnt; k += 256) {
    int dl = (unsigned)seg[k].x >> 24;
    atomicAdd(&hist[dl], 1);
    atomicAdd(&degf[dl], __int_as_float(seg[k].y));
  }
  __syncthreads();
  int v = (tid < BSZ) ? hist[tid] : 0;
  for (int o = 1; o < BSZ; o <<= 1) {
    int t = (tid < BSZ && tid >= o) ? hist[tid - o] : 0;
    __syncthreads();
    if (tid < BSZ) hist[tid] += t;
    __syncthreads();
  }
  if (tid < BSZ) {
    int excl = hist[tid] - v;
    curs[tid] = excl;
    int node = b * BSZ + tid;
    if (node < N) {
      off[node] = bstart + excl;
      degN[node] = v;
      dinv[node] = rsqrtf(1.0f + degf[tid]);
    }
  }
  __syncthreads();
  for (int k = tid; k < cnt; k += 256) {
    int2 ev = seg[k];
    int dl = (unsigned)ev.x >> 24;
    int slot = atomicAdd(&curs[dl], 1);
    gD[bstart + slot] = make_int2(ev.x & 0xFFFFFF, ev.y);
  }
}

// ------- per-src-slab weighted out-degree (dw) + global max -------
__global__ void k_dw(const unsigned* __restrict__ gS, const int* __restrict__ cursS_g,
                     float* __restrict__ dw, unsigned* maxbits, int NBS, int N) {
  __shared__ float acc[BSZS];
  int tid = threadIdx.x, b = blockIdx.x;
  int bstart = b * SLAB_S;
  int bend = cursS_g[b];
  acc[tid] = 0.f;
  __syncthreads();
  for (int k = bstart + tid; k < bend; k += BSZS) {
    unsigned p = gS[k];
    atomicAdd(&acc[p >> 16], __half2float(__ushort_as_half((unsigned short)(p & 0xFFFFu))));
  }
  __syncthreads();
  float m = 0.f;
  int node = b * BSZS + tid;
  if (node < N) { dw[node] = acc[tid]; m = acc[tid]; }
  for (int mm = 32; mm; mm >>= 1) m = fmaxf(m, __shfl_xor(m, mm, 64));
  if ((tid & 63) == 0) atomicMax(maxbits, __float_as_uint(m));
}

// ------- g0 = dinv[i] * (x @ W1) row, MFMA 16x16x32 bf16, stored fp8 e4m3 -------
// A: row=l&15, k=(l>>4)*8+i ; B: col=l&15, k=(l>>4)*8+i ; D: col=l&15, row=(l>>4)*4+reg
__global__ void k_gemm1(const float* __restrict__ x, const float* __restrict__ W1,
                        const float* __restrict__ dinv, unsigned char* __restrict__ g0, int N) {
  int lane = threadIdx.x & 63;
  int wid = (blockIdx.x * blockDim.x + threadIdx.x) >> 6;
  int nw = (gridDim.x * blockDim.x) >> 6;
  int l16 = lane & 15, lh = lane >> 4;
  bf16x8 bfrag[4][4];
#pragma unroll
  for (int cb = 0; cb < 4; ++cb)
#pragma unroll
    for (int kf = 0; kf < 4; ++kf)
#pragma unroll
      for (int i = 0; i < 8; ++i) {
        int k = kf * 32 + lh * 8 + i;
        bfrag[cb][kf][i] = f32_bf16(W1[k * F_HID + cb * 16 + l16]);
      }
  int ntiles = (N + 15) >> 4;
  for (int t = wid; t < ntiles; t += nw) {
    int rowbase = t << 4;
    int row = min(rowbase + l16, N - 1);
    bf16x8 afrag[4];
#pragma unroll
    for (int kf = 0; kf < 4; ++kf) {
      const f32x4* xp = (const f32x4*)(x + (size_t)row * F_IN + kf * 32 + lh * 8);
      f32x4 v0 = xp[0], v1 = xp[1];
#pragma unroll
      for (int i = 0; i < 4; ++i) afrag[kf][i] = f32_bf16(v0[i]);
#pragma unroll
      for (int i = 0; i < 4; ++i) afrag[kf][4 + i] = f32_bf16(v1[i]);
    }
    f32x4 acc[4] = {{0.f,0.f,0.f,0.f},{0.f,0.f,0.f,0.f},{0.f,0.f,0.f,0.f},{0.f,0.f,0.f,0.f}};
#pragma unroll
    for (int cb = 0; cb < 4; ++cb)
#pragma unroll
      for (int kf = 0; kf < 4; ++kf)
        acc[cb] = __builtin_amdgcn_mfma_f32_16x16x32_bf16(afrag[kf], bfrag[cb][kf], acc[cb], 0, 0, 0);
    if (rowbase + 16 <= N) {
      f32x4 dv = *(const f32x4*)(dinv + rowbase + lh * 4);
#pragma unroll
      for (int cb = 0; cb < 4; ++cb)
#pragma unroll
        for (int r = 0; r < 4; ++r) {
          int rr = rowbase + lh * 4 + r;
          g0[(size_t)rr * F_HID + cb * 16 + l16] = f32_to_fp8(acc[cb][r] * dv[r]);
        }
    } else {
#pragma unroll
      for (int cb = 0; cb < 4; ++cb)
#pragma unroll
        for (int r = 0; r < 4; ++r) {
          int rr = rowbase + lh * 4 + r;
          if (rr < N)
            g0[(size_t)rr * F_HID + cb * 16 + l16] = f32_to_fp8(acc[cb][r] * dinv[rr]);
        }
    }
  }
}

// ------- layer-1 agg: wave per node; 8 edge-slots x 8 lanes x 8 features; pk-fma -------
__global__ void k_agg1(const unsigned char* __restrict__ g0, const float* __restrict__ dinv,
                       const int* __restrict__ off, const int* __restrict__ degN,
                       const int2* __restrict__ csr,
                       const float* __restrict__ b1, const float* __restrict__ W2,
                       float* __restrict__ u, int N) {
  int lane = threadIdx.x & 63;
  int grp = lane >> 3;        // edge slot 0..7
  int l8  = lane & 7;         // feature octet 0..7
  int i = (blockIdx.x * blockDim.x + threadIdx.x) >> 6;
  if (i >= N) return;
  const uint2* g0v = (const uint2*)g0;
  f32x2 acc2[4] = {{0.f,0.f},{0.f,0.f},{0.f,0.f},{0.f,0.f}};
  if (grp == 0) {             // self contribution once (group 0)
    uint2 rv = g0v[(size_t)i * 8 + l8];
    acc2[0] += __builtin_amdgcn_cvt_pk_f32_fp8(rv.x, false);
    acc2[1] += __builtin_amdgcn_cvt_pk_f32_fp8(rv.x, true);
    acc2[2] += __builtin_amdgcn_cvt_pk_f32_fp8(rv.y, false);
    acc2[3] += __builtin_amdgcn_cvt_pk_f32_fp8(rv.y, true);
  }
  int p0 = off[i], p1 = p0 + degN[i];
  for (int p = p0; p < p1; p += 64) {
    int m = min(p1 - p, 64);
    int2 ed = make_int2(0, 0);
    if (lane < m) ed = csr[p + lane];
#pragma unroll
    for (int jj = 0; jj < 8; ++jj) {
      int j = jj * 8 + grp;
      int s = __shfl(ed.x, j, 64);
      float w = __int_as_float(__shfl(ed.y, j, 64));
      if (j < m) {
        uint2 rv = g0v[(size_t)s * 8 + l8];
        f32x2 w2; w2.x = w; w2.y = w;
        acc2[0] = __builtin_elementwise_fma(__builtin_amdgcn_cvt_pk_f32_fp8(rv.x, false), w2, acc2[0]);
        acc2[1] = __builtin_elementwise_fma(__builtin_amdgcn_cvt_pk_f32_fp8(rv.x, true),  w2, acc2[1]);
        acc2[2] = __builtin_elementwise_fma(__builtin_amdgcn_cvt_pk_f32_fp8(rv.y, false), w2, acc2[2]);
        acc2[3] = __builtin_elementwise_fma(__builtin_amdgcn_cvt_pk_f32_fp8(rv.y, true),  w2, acc2[3]);
      }
    }
  }
  float acc[8] = {acc2[0].x, acc2[0].y, acc2[1].x, acc2[1].y,
                  acc2[2].x, acc2[2].y, acc2[3].x, acc2[3].y};
#pragma unroll
  for (int k = 0; k < 8; ++k) {
    acc[k] += __shfl_xor(acc[k], 8, 64);
    acc[k] += __shfl_xor(acc[k], 16, 64);
    acc[k] += __shfl_xor(acc[k], 32, 64);
  }
  float di = dinv[i];
  float pdt = 0.f;
#pragma unroll
  for (int k = 0; k < 8; ++k) {
    int f = l8 * 8 + k;
    float h = fmaxf(di * acc[k] + b1[f], 0.f);
    pdt = fmaf(h, W2[f], pdt);
  }
  pdt += __shfl_xor(pdt, 1, 64);
  pdt += __shfl_xor(pdt, 2, 64);
  pdt += __shfl_xor(pdt, 4, 64);
  if (lane == 0) u[i] = di * pdt;
}

// ------- layer-2 agg + final: 2 nodes per wave (32-lane groups) -------
__global__ void k_agg2_final(const float* __restrict__ u, const float* __restrict__ dinv,
                             const int* __restrict__ off, const int* __restrict__ degN,
                             const int2* __restrict__ csr,
                             const float* __restrict__ b2, const float* __restrict__ dw,
                             const unsigned* __restrict__ maxbits,
                             float* __restrict__ out, int N) {
  int lane32 = threadIdx.x & 31;
  int i = blockIdx.x * 8 + (threadIdx.x >> 5);   // 8 nodes per 256-thread block
  if (i >= N) return;
  float acc = (lane32 == 0) ? u[i] : 0.f;        // self (u_i)
  int p0 = off[i], p1 = p0 + degN[i];
  for (int p = p0 + lane32; p < p1; p += 32) {
    int2 ed = csr[p];
    acc = fmaf(__int_as_float(ed.y), u[ed.x], acc);
  }
  for (int mm = 16; mm; mm >>= 1) acc += __shfl_xor(acc, mm, 64);
  if (lane32 == 0) {
    float md = __uint_as_float(*maxbits);
    float z = dinv[i] * acc + b2[0];
    float sc = 1.0f / (1.0f + expf(-z));
    out[i] = sc * (1.0f + dw[i] / md);
  }
}

extern "C" void kernel_launch(void* const* d_in, const int* in_sizes, int n_in,
                              void* d_out, int out_size, void* d_ws, size_t ws_size,
                              hipStream_t stream) {
  const float* x  = (const float*)d_in[0];
  const int*   ei = (const int*)d_in[1];
  const float* ew = (const float*)d_in[2];
  const float* W1 = (const float*)d_in[3];
  const float* b1 = (const float*)d_in[4];
  const float* W2 = (const float*)d_in[5];
  const float* b2 = (const float*)d_in[6];
  float* out = (float*)d_out;

  int N = out_size;      // 100000
  int E = in_sizes[2];   // 3200000
  const int* src = ei;
  const int* dst = ei + E;

  int NBD = (N + BSZ - 1) >> BSH;       // 782
  int NBS = (N + BSZS - 1) >> BSHS;     // 98
  size_t slabD = (size_t)NBD * SLAB_D;  // 3.60M entries
  size_t slabS = (size_t)NBS * SLAB_S;  // 3.41M entries

  char* w8 = (char*)d_ws;
  int2*     gD    = (int2*)w8;                        // slabD int2 (28.8 MB; becomes CSR)
  unsigned* gS    = (unsigned*)(gD + slabD);          // slabS u32 (13.6 MB)
  unsigned char* g0 = (unsigned char*)(gS + slabS);   // N*64 fp8 (6.4 MB)
  int*      cursD = (int*)(g0 + (size_t)N * F_HID);   // NBD
  int*      cursS = cursD + NBD;                      // NBS
  int*      off   = cursS + NBS;                      // N
  int*      degN  = off + N;                          // N
  float*    dinv  = (float*)(degN + N);               // N
  float*    dw    = dinv + N;                         // N
  float*    u     = dw + N;                           // N
  unsigned* maxbits = (unsigned*)(u + N);             // 1

  k_init0<<<1, 1024, 0, stream>>>(cursD, cursS, maxbits, NBD, NBS);
  k_part<<<NWG, PT, 0, stream>>>(src, dst, ew, cursD, cursS, gD, gS, NBD, NBS, E);
  k_csr<<<NBD, 256, 0, stream>>>(gD, cursD, off, degN, dinv, NBD, N);
  k_dw<<<NBS, BSZS, 0, stream>>>(gS, cursS, dw, maxbits, NBS, N);
  k_gemm1<<<256, 256, 0, stream>>>(x, W1, dinv, g0, N);
  k_agg1<<<(N * 64 + 255) / 256, 256, 0, stream>>>(g0, dinv, off, degN, gD, b1, W2, u, N);
  k_agg2_final<<<(N + 7) / 8, 256, 0, stream>>>(u, dinv, off, degN, gD, b2, dw, maxbits, out, N);
}

// Round 22
// 258.951 us; speedup vs baseline: 1.0775x; 1.0036x over previous
//
#include <hip/hip_runtime.h>
#include <hip/hip_fp16.h>
#include <math.h>

#define F_IN 128
#define F_HID 64
#define NWG 512      // partition chunks (one sub-chunk per block; 2 blocks/CU)
#define PT 1024      // threads per partition block
#define BSH 7        // dst bucket shift (128 nodes per bucket)
#define BSZ 128
#define BSHS 10      // src bucket shift (1024 nodes per bucket)
#define BSZS 1024
#define SLAB_D 4608  // dst slab capacity (mean 4096, +8 sigma; proven r12/r20)
#define SLAB_S 34816 // src slab capacity (mean 32653, +12 sigma)
#define SEGCAP 6144  // LDS staging for k_csr (>= SLAB_D)
#define SUBC 6272    // k_part sub-chunk capacity (>= ceil(E/NWG) = 6250)

typedef float f32x2 __attribute__((ext_vector_type(2)));
typedef float f32x4 __attribute__((ext_vector_type(4)));
typedef __bf16 bf16x8 __attribute__((ext_vector_type(8)));

// ---- fp8 e4m3 (OCP, gfx950 HW cvt) ----
__device__ __forceinline__ unsigned char f32_to_fp8(float v) {
  unsigned r = __builtin_amdgcn_cvt_pk_fp8_f32(v, v, 0, false);
  return (unsigned char)(r & 0xFFu);
}

// ---- f32 -> bf16 RTNE (bit-manip) ----
__device__ __forceinline__ __bf16 f32_bf16(float f) {
  unsigned u = __float_as_uint(f);
  unsigned r = (u + 0x7FFFu + ((u >> 16) & 1u)) >> 16;
  return __builtin_bit_cast(__bf16, (unsigned short)r);
}

// ------- init: slab cursors + maxbits -------
__global__ void k_init0(int* cursD, int* cursS, unsigned* maxbits, int NBD, int NBS) {
  int t = threadIdx.x;
  for (int b = t; b < NBD; b += 1024) cursD[b] = b * SLAB_D;
  for (int b = t; b < NBS; b += 1024) cursS[b] = b * SLAB_S;
  if (t == 0) *maxbits = 0u;
}

// ------- partition: per sub-chunk LDS sort + global slab reservation, dense writes -------
__global__ void __launch_bounds__(PT) k_part(
    const int* __restrict__ src, const int* __restrict__ dst,
    const float* __restrict__ ew, int* cursD_g, int* cursS_g,
    int2* __restrict__ gD, unsigned* __restrict__ gS,
    int NBD, int NBS, int E) {
  __shared__ int2 seg[SUBC];              // 50 KB sorted staging
  __shared__ unsigned short bkt[SUBC];    // 12.5 KB bucket tag per sorted slot
  __shared__ int lcur[784];               // hist -> LDS scatter cursor
  __shared__ int excl[784];               // per-subchunk exclusive offsets (LDS slots)
  __shared__ int gbase[784];              // reserved global window base per bucket
  __shared__ int scanT[1024];
  __shared__ int hS[104];                 // src hist
  __shared__ int baseS[104];              // reserved src window base
  __shared__ int lcurS[104];              // src scatter cursor
  int tid = threadIdx.x, w = blockIdx.x;
  int C = (E + NWG - 1) / NWG;
  int e0 = w * C, e1 = min(E, e0 + C);
  for (int c0 = e0; c0 < e1; c0 += SUBC) {
    int cnt = min(SUBC, e1 - c0);
    for (int b = tid; b < NBD; b += PT) lcur[b] = 0;
    if (tid < NBS) { hS[tid] = 0; lcurS[tid] = 0; }
    __syncthreads();
    // pass1: histograms (dst fine, src coarse)
    for (int k = tid; k < cnt; k += PT) {
      int e = c0 + k;
      atomicAdd(&lcur[dst[e] >> BSH], 1);
      atomicAdd(&hS[src[e] >> BSHS], 1);
    }
    __syncthreads();
    // reserve global windows (one atomic per non-empty bucket per sub-chunk)
    for (int b = tid; b < NBD; b += PT) {
      int c = lcur[b];
      gbase[b] = c ? atomicAdd(&cursD_g[b], c) : 0;
    }
    if (tid < NBS) {
      int c = hS[tid];
      baseS[tid] = c ? atomicAdd(&cursS_g[tid], c) : 0;
    }
    // scan dst hist -> LDS slot offsets
    int v = (tid < NBD) ? lcur[tid] : 0;
    scanT[tid] = v;
    __syncthreads();
    for (int o = 1; o < 1024; o <<= 1) {
      int t = (tid >= o) ? scanT[tid - o] : 0;
      __syncthreads();
      scanT[tid] += t;
      __syncthreads();
    }
    if (tid < NBD) { excl[tid] = scanT[tid] - v; lcur[tid] = scanT[tid] - v; }
    __syncthreads();
    // pass2: scatter dst edges into bucket-sorted LDS; src edges direct to window
    for (int k = tid; k < cnt; k += PT) {
      int e = c0 + k;
      int s = src[e], d = dst[e];
      float wv = ew[e];
      int b = d >> BSH;
      int slot = atomicAdd(&lcur[b], 1);
      seg[slot] = make_int2(s | ((d & (BSZ - 1)) << 24), __float_as_int(wv));
      bkt[slot] = (unsigned short)b;
      int bs = s >> BSHS;
      int slotS = atomicAdd(&lcurS[bs], 1);
      gS[baseS[bs] + slotS] = ((unsigned)(s & (BSZS - 1)) << 16)
                            | (unsigned)__half_as_ushort(__float2half(wv));
    }
    __syncthreads();
    // pass3: dense write-out to reserved windows
    for (int k = tid; k < cnt; k += PT) {
      int b = bkt[k];
      gD[gbase[b] + (k - excl[b])] = seg[k];
    }
    __syncthreads();
  }
}

// ------- per-dst-bucket local counting sort -> CSR (in place) + off/degN/dinv -------
__global__ void k_csr(int2* __restrict__ gD, const int* __restrict__ cursD_g,
                      int* __restrict__ off, int* __restrict__ degN,
                      float* __restrict__ dinv, int NBD, int N) {
  __shared__ int2 seg[SEGCAP];
  __shared__ int hist[BSZ];
  __shared__ int curs[BSZ];
  __shared__ float degf[BSZ];
  int tid = threadIdx.x, b = blockIdx.x;
  int bstart = b * SLAB_D;
  int bend = cursD_g[b];
  int cnt = bend - bstart;
  for (int k = tid; k < cnt; k += 256) seg[k] = gD[bstart + k];
  if (tid < BSZ) { hist[tid] = 0; degf[tid] = 0.f; }
  __syncthreads();
  for (int k = tid; k < cnt; k += 256) {
    int dl = (unsigned)seg[k].x >> 24;
    atomicAdd(&hist[dl], 1);
    atomicAdd(&degf[dl], __int_as_float(seg[k].y));
  }
  __syncthreads();
  int v = (tid < BSZ) ? hist[tid] : 0;
  for (int o = 1; o < BSZ; o <<= 1) {
    int t = (tid < BSZ && tid >= o) ? hist[tid - o] : 0;
    __syncthreads();
    if (tid < BSZ) hist[tid] += t;
    __syncthreads();
  }
  if (tid < BSZ) {
    int excl = hist[tid] - v;
    curs[tid] = excl;
    int node = b * BSZ + tid;
    if (node < N) {
      off[node] = bstart + excl;
      degN[node] = v;
      dinv[node] = rsqrtf(1.0f + degf[tid]);
    }
  }
  __syncthreads();
  for (int k = tid; k < cnt; k += 256) {
    int2 ev = seg[k];
    int dl = (unsigned)ev.x >> 24;
    int slot = atomicAdd(&curs[dl], 1);
    gD[bstart + slot] = make_int2(ev.x & 0xFFFFFF, ev.y);
  }
}

// ------- per-src-slab weighted out-degree (dw) + global max -------
__global__ void k_dw(const unsigned* __restrict__ gS, const int* __restrict__ cursS_g,
                     float* __restrict__ dw, unsigned* maxbits, int NBS, int N) {
  __shared__ float acc[BSZS];
  int tid = threadIdx.x, b = blockIdx.x;
  int bstart = b * SLAB_S;
  int bend = cursS_g[b];
  acc[tid] = 0.f;
  __syncthreads();
  for (int k = bstart + tid; k < bend; k += BSZS) {
    unsigned p = gS[k];
    atomicAdd(&acc[p >> 16], __half2float(__ushort_as_half((unsigned short)(p & 0xFFFFu))));
  }
  __syncthreads();
  float m = 0.f;
  int node = b * BSZS + tid;
  if (node < N) { dw[node] = acc[tid]; m = acc[tid]; }
  for (int mm = 32; mm; mm >>= 1) m = fmaxf(m, __shfl_xor(m, mm, 64));
  if ((tid & 63) == 0) atomicMax(maxbits, __float_as_uint(m));
}

// ------- g0 = dinv[i] * (x @ W1) row, MFMA 16x16x32 bf16, stored fp8 e4m3 -------
// A: row=l&15, k=(l>>4)*8+i ; B: col=l&15, k=(l>>4)*8+i ; D: col=l&15, row=(l>>4)*4+reg
__global__ void k_gemm1(const float* __restrict__ x, const float* __restrict__ W1,
                        const float* __restrict__ dinv, unsigned char* __restrict__ g0, int N) {
  int lane = threadIdx.x & 63;
  int wid = (blockIdx.x * blockDim.x + threadIdx.x) >> 6;
  int nw = (gridDim.x * blockDim.x) >> 6;
  int l16 = lane & 15, lh = lane >> 4;
  bf16x8 bfrag[4][4];
#pragma unroll
  for (int cb = 0; cb < 4; ++cb)
#pragma unroll
    for (int kf = 0; kf < 4; ++kf)
#pragma unroll
      for (int i = 0; i < 8; ++i) {
        int k = kf * 32 + lh * 8 + i;
        bfrag[cb][kf][i] = f32_bf16(W1[k * F_HID + cb * 16 + l16]);
      }
  int ntiles = (N + 15) >> 4;
  for (int t = wid; t < ntiles; t += nw) {
    int rowbase = t << 4;
    int row = min(rowbase + l16, N - 1);
    bf16x8 afrag[4];
#pragma unroll
    for (int kf = 0; kf < 4; ++kf) {
      const f32x4* xp = (const f32x4*)(x + (size_t)row * F_IN + kf * 32 + lh * 8);
      f32x4 v0 = xp[0], v1 = xp[1];
#pragma unroll
      for (int i = 0; i < 4; ++i) afrag[kf][i] = f32_bf16(v0[i]);
#pragma unroll
      for (int i = 0; i < 4; ++i) afrag[kf][4 + i] = f32_bf16(v1[i]);
    }
    f32x4 acc[4] = {{0.f,0.f,0.f,0.f},{0.f,0.f,0.f,0.f},{0.f,0.f,0.f,0.f},{0.f,0.f,0.f,0.f}};
#pragma unroll
    for (int cb = 0; cb < 4; ++cb)
#pragma unroll
      for (int kf = 0; kf < 4; ++kf)
        acc[cb] = __builtin_amdgcn_mfma_f32_16x16x32_bf16(afrag[kf], bfrag[cb][kf], acc[cb], 0, 0, 0);
    if (rowbase + 16 <= N) {
      f32x4 dv = *(const f32x4*)(dinv + rowbase + lh * 4);
#pragma unroll
      for (int cb = 0; cb < 4; ++cb)
#pragma unroll
        for (int r = 0; r < 4; ++r) {
          int rr = rowbase + lh * 4 + r;
          g0[(size_t)rr * F_HID + cb * 16 + l16] = f32_to_fp8(acc[cb][r] * dv[r]);
        }
    } else {
#pragma unroll
      for (int cb = 0; cb < 4; ++cb)
#pragma unroll
        for (int r = 0; r < 4; ++r) {
          int rr = rowbase + lh * 4 + r;
          if (rr < N)
            g0[(size_t)rr * F_HID + cb * 16 + l16] = f32_to_fp8(acc[cb][r] * dinv[rr]);
        }
    }
  }
}

// ------- layer-1 agg: wave per node; 8 edge-slots x 8 lanes x 8 features; pk-fma -------
// jj trip count is dynamic: mean deg = 32 -> only ~4 of 8 slots populated per batch.
__global__ void k_agg1(const unsigned char* __restrict__ g0, const float* __restrict__ dinv,
                       const int* __restrict__ off, const int* __restrict__ degN,
                       const int2* __restrict__ csr,
                       const float* __restrict__ b1, const float* __restrict__ W2,
                       float* __restrict__ u, int N) {
  int lane = threadIdx.x & 63;
  int grp = lane >> 3;        // edge slot 0..7
  int l8  = lane & 7;         // feature octet 0..7
  int i = (blockIdx.x * blockDim.x + threadIdx.x) >> 6;
  if (i >= N) return;
  const uint2* g0v = (const uint2*)g0;
  f32x2 acc2[4] = {{0.f,0.f},{0.f,0.f},{0.f,0.f},{0.f,0.f}};
  if (grp == 0) {             // self contribution once (group 0)
    uint2 rv = g0v[(size_t)i * 8 + l8];
    acc2[0] += __builtin_amdgcn_cvt_pk_f32_fp8(rv.x, false);
    acc2[1] += __builtin_amdgcn_cvt_pk_f32_fp8(rv.x, true);
    acc2[2] += __builtin_amdgcn_cvt_pk_f32_fp8(rv.y, false);
    acc2[3] += __builtin_amdgcn_cvt_pk_f32_fp8(rv.y, true);
  }
  int p0 = off[i], p1 = p0 + degN[i];
  for (int p = p0; p < p1; p += 64) {
    int m = min(p1 - p, 64);
    int2 ed = make_int2(0, 0);
    if (lane < m) ed = csr[p + lane];
    int jmax = (m + 7) >> 3;              // dynamic: skip fully-empty edge slots
    for (int jj = 0; jj < jmax; ++jj) {
      int j = jj * 8 + grp;
      int s = __shfl(ed.x, j, 64);
      float w = __int_as_float(__shfl(ed.y, j, 64));
      if (j < m) {
        uint2 rv = g0v[(size_t)s * 8 + l8];
        f32x2 w2; w2.x = w; w2.y = w;
        acc2[0] = __builtin_elementwise_fma(__builtin_amdgcn_cvt_pk_f32_fp8(rv.x, false), w2, acc2[0]);
        acc2[1] = __builtin_elementwise_fma(__builtin_amdgcn_cvt_pk_f32_fp8(rv.x, true),  w2, acc2[1]);
        acc2[2] = __builtin_elementwise_fma(__builtin_amdgcn_cvt_pk_f32_fp8(rv.y, false), w2, acc2[2]);
        acc2[3] = __builtin_elementwise_fma(__builtin_amdgcn_cvt_pk_f32_fp8(rv.y, true),  w2, acc2[3]);
      }
    }
  }
  float acc[8] = {acc2[0].x, acc2[0].y, acc2[1].x, acc2[1].y,
                  acc2[2].x, acc2[2].y, acc2[3].x, acc2[3].y};
#pragma unroll
  for (int k = 0; k < 8; ++k) {
    acc[k] += __shfl_xor(acc[k], 8, 64);
    acc[k] += __shfl_xor(acc[k], 16, 64);
    acc[k] += __shfl_xor(acc[k], 32, 64);
  }
  float di = dinv[i];
  float pdt = 0.f;
#pragma unroll
  for (int k = 0; k < 8; ++k) {
    int f = l8 * 8 + k;
    float h = fmaxf(di * acc[k] + b1[f], 0.f);
    pdt = fmaf(h, W2[f], pdt);
  }
  pdt += __shfl_xor(pdt, 1, 64);
  pdt += __shfl_xor(pdt, 2, 64);
  pdt += __shfl_xor(pdt, 4, 64);
  if (lane == 0) u[i] = di * pdt;
}

// ------- layer-2 agg + final: 2 nodes per wave (32-lane groups) -------
__global__ void k_agg2_final(const float* __restrict__ u, const float* __restrict__ dinv,
                             const int* __restrict__ off, const int* __restrict__ degN,
                             const int2* __restrict__ csr,
                             const float* __restrict__ b2, const float* __restrict__ dw,
                             const unsigned* __restrict__ maxbits,
                             float* __restrict__ out, int N) {
  int lane32 = threadIdx.x & 31;
  int i = blockIdx.x * 8 + (threadIdx.x >> 5);   // 8 nodes per 256-thread block
  if (i >= N) return;
  float acc = (lane32 == 0) ? u[i] : 0.f;        // self (u_i)
  int p0 = off[i], p1 = p0 + degN[i];
  for (int p = p0 + lane32; p < p1; p += 32) {
    int2 ed = csr[p];
    acc = fmaf(__int_as_float(ed.y), u[ed.x], acc);
  }
  for (int mm = 16; mm; mm >>= 1) acc += __shfl_xor(acc, mm, 64);
  if (lane32 == 0) {
    float md = __uint_as_float(*maxbits);
    float z = dinv[i] * acc + b2[0];
    float sc = 1.0f / (1.0f + expf(-z));
    out[i] = sc * (1.0f + dw[i] / md);
  }
}

extern "C" void kernel_launch(void* const* d_in, const int* in_sizes, int n_in,
                              void* d_out, int out_size, void* d_ws, size_t ws_size,
                              hipStream_t stream) {
  const float* x  = (const float*)d_in[0];
  const int*   ei = (const int*)d_in[1];
  const float* ew = (const float*)d_in[2];
  const float* W1 = (const float*)d_in[3];
  const float* b1 = (const float*)d_in[4];
  const float* W2 = (const float*)d_in[5];
  const float* b2 = (const float*)d_in[6];
  float* out = (float*)d_out;

  int N = out_size;      // 100000
  int E = in_sizes[2];   // 3200000
  const int* src = ei;
  const int* dst = ei + E;

  int NBD = (N + BSZ - 1) >> BSH;       // 782
  int NBS = (N + BSZS - 1) >> BSHS;     // 98
  size_t slabD = (size_t)NBD * SLAB_D;  // 3.60M entries
  size_t slabS = (size_t)NBS * SLAB_S;  // 3.41M entries

  char* w8 = (char*)d_ws;
  int2*     gD    = (int2*)w8;                        // slabD int2 (28.8 MB; becomes CSR)
  unsigned* gS    = (unsigned*)(gD + slabD);          // slabS u32 (13.6 MB)
  unsigned char* g0 = (unsigned char*)(gS + slabS);   // N*64 fp8 (6.4 MB)
  int*      cursD = (int*)(g0 + (size_t)N * F_HID);   // NBD
  int*      cursS = cursD + NBD;                      // NBS
  int*      off   = cursS + NBS;                      // N
  int*      degN  = off + N;                          // N
  float*    dinv  = (float*)(degN + N);               // N
  float*    dw    = dinv + N;                         // N
  float*    u     = dw + N;                           // N
  unsigned* maxbits = (unsigned*)(u + N);             // 1

  k_init0<<<1, 1024, 0, stream>>>(cursD, cursS, maxbits, NBD, NBS);
  k_part<<<NWG, PT, 0, stream>>>(src, dst, ew, cursD, cursS, gD, gS, NBD, NBS, E);
  k_csr<<<NBD, 256, 0, stream>>>(gD, cursD, off, degN, dinv, NBD, N);
  k_dw<<<NBS, BSZS, 0, stream>>>(gS, cursS, dw, maxbits, NBS, N);
  k_gemm1<<<256, 256, 0, stream>>>(x, W1, dinv, g0, N);
  k_agg1<<<(N * 64 + 255) / 256, 256, 0, stream>>>(g0, dinv, off, degN, gD, b1, W2, u, N);
  k_agg2_final<<<(N + 7) / 8, 256, 0, stream>>>(u, dinv, off, degN, gD, b2, dw, maxbits, out, N);
}

// Round 23
// 255.094 us; speedup vs baseline: 1.0937x; 1.0151x over previous
//
#include <hip/hip_runtime.h>
#include <hip/hip_fp16.h>
#include <math.h>

#define F_IN 128
#define F_HID 64
#define NWG 512      // partition chunks (one sub-chunk per block; 2 blocks/CU)
#define PT 1024      // threads per partition block
#define BSH 7        // dst bucket shift (128 nodes per bucket)
#define BSZ 128
#define BSHS 10      // src bucket shift (1024 nodes per bucket)
#define BSZS 1024
#define SLAB_D 4608  // dst slab capacity (mean 4096, +8 sigma; proven r12/r20)
#define SLAB_S 34816 // src slab capacity (mean 32653, +12 sigma)
#define SEGCAP 6144  // LDS staging for k_csr (>= SLAB_D)
#define SUBC 6272    // k_part sub-chunk capacity (>= ceil(E/NWG) = 6250)
#define CSRT 512     // k_csr threads per block

typedef float f32x2 __attribute__((ext_vector_type(2)));
typedef float f32x4 __attribute__((ext_vector_type(4)));
typedef __bf16 bf16x8 __attribute__((ext_vector_type(8)));

// ---- fp8 e4m3 (OCP, gfx950 HW cvt) ----
__device__ __forceinline__ unsigned char f32_to_fp8(float v) {
  unsigned r = __builtin_amdgcn_cvt_pk_fp8_f32(v, v, 0, false);
  return (unsigned char)(r & 0xFFu);
}

// ---- f32 -> bf16 RTNE (bit-manip) ----
__device__ __forceinline__ __bf16 f32_bf16(float f) {
  unsigned u = __float_as_uint(f);
  unsigned r = (u + 0x7FFFu + ((u >> 16) & 1u)) >> 16;
  return __builtin_bit_cast(__bf16, (unsigned short)r);
}

// ------- init: slab cursors + maxbits -------
__global__ void k_init0(int* cursD, int* cursS, unsigned* maxbits, int NBD, int NBS) {
  int t = threadIdx.x;
  for (int b = t; b < NBD; b += 1024) cursD[b] = b * SLAB_D;
  for (int b = t; b < NBS; b += 1024) cursS[b] = b * SLAB_S;
  if (t == 0) *maxbits = 0u;
}

// ------- partition: per sub-chunk LDS sort + global slab reservation, dense writes -------
// scan via wave-level shfl (3 barriers instead of 20)
__global__ void __launch_bounds__(PT) k_part(
    const int* __restrict__ src, const int* __restrict__ dst,
    const float* __restrict__ ew, int* cursD_g, int* cursS_g,
    int2* __restrict__ gD, unsigned* __restrict__ gS,
    int NBD, int NBS, int E) {
  __shared__ int2 seg[SUBC];              // 50 KB sorted staging
  __shared__ unsigned short bkt[SUBC];    // 12.5 KB bucket tag per sorted slot
  __shared__ int lcur[784];               // hist -> LDS scatter cursor
  __shared__ int excl[784];               // per-subchunk exclusive offsets (LDS slots)
  __shared__ int gbase[784];              // reserved global window base per bucket
  __shared__ int wsum[16];                // per-wave scan totals
  __shared__ int hS[104];                 // src hist
  __shared__ int baseS[104];              // reserved src window base
  __shared__ int lcurS[104];              // src scatter cursor
  int tid = threadIdx.x, w = blockIdx.x;
  int lane = tid & 63, wv = tid >> 6;     // 16 waves
  int C = (E + NWG - 1) / NWG;
  int e0 = w * C, e1 = min(E, e0 + C);
  for (int c0 = e0; c0 < e1; c0 += SUBC) {
    int cnt = min(SUBC, e1 - c0);
    for (int b = tid; b < NBD; b += PT) lcur[b] = 0;
    if (tid < NBS) { hS[tid] = 0; lcurS[tid] = 0; }
    __syncthreads();
    // pass1: histograms (dst fine, src coarse)
    for (int k = tid; k < cnt; k += PT) {
      int e = c0 + k;
      atomicAdd(&lcur[dst[e] >> BSH], 1);
      atomicAdd(&hS[src[e] >> BSHS], 1);
    }
    __syncthreads();
    // reserve global windows (one atomic per non-empty bucket per sub-chunk)
    for (int b = tid; b < NBD; b += PT) {
      int c = lcur[b];
      gbase[b] = c ? atomicAdd(&cursD_g[b], c) : 0;
    }
    if (tid < NBS) {
      int c = hS[tid];
      baseS[tid] = c ? atomicAdd(&cursS_g[tid], c) : 0;
    }
    // wave-level exclusive scan of lcur[0..NBD)
    int v = (tid < NBD) ? lcur[tid] : 0;
    int x = v;
#pragma unroll
    for (int o = 1; o < 64; o <<= 1) {
      int y = __shfl_up(x, o, 64);
      if (lane >= o) x += y;
    }
    if (lane == 63) wsum[wv] = x;         // wave total
    __syncthreads();
    if (wv == 0 && lane < 16) {
      int s = wsum[lane];
#pragma unroll
      for (int o = 1; o < 16; o <<= 1) {
        int y = __shfl_up(s, o, 64);
        if (lane >= o) s += y;
      }
      wsum[lane] = s;                     // inclusive wave-prefix
    }
    __syncthreads();
    int base = (wv > 0) ? wsum[wv - 1] : 0;
    int ex = base + x - v;                // exclusive prefix for this tid
    if (tid < NBD) { excl[tid] = ex; lcur[tid] = ex; }
    __syncthreads();
    // pass2: scatter dst edges into bucket-sorted LDS; src edges direct to window
    for (int k = tid; k < cnt; k += PT) {
      int e = c0 + k;
      int s = src[e], d = dst[e];
      float wvv = ew[e];
      int b = d >> BSH;
      int slot = atomicAdd(&lcur[b], 1);
      seg[slot] = make_int2(s | ((d & (BSZ - 1)) << 24), __float_as_int(wvv));
      bkt[slot] = (unsigned short)b;
      int bs = s >> BSHS;
      int slotS = atomicAdd(&lcurS[bs], 1);
      gS[baseS[bs] + slotS] = ((unsigned)(s & (BSZS - 1)) << 16)
                            | (unsigned)__half_as_ushort(__float2half(wvv));
    }
    __syncthreads();
    // pass3: dense write-out to reserved windows
    for (int k = tid; k < cnt; k += PT) {
      int b = bkt[k];
      gD[gbase[b] + (k - excl[b])] = seg[k];
    }
    __syncthreads();
  }
}

// ------- per-dst-bucket local counting sort -> CSR (in place) + off/degN/dinv -------
__global__ void __launch_bounds__(CSRT) k_csr(
    int2* __restrict__ gD, const int* __restrict__ cursD_g,
    int* __restrict__ off, int* __restrict__ degN,
    float* __restrict__ dinv, int NBD, int N) {
  __shared__ int2 seg[SEGCAP];
  __shared__ int hist[BSZ];
  __shared__ int curs[BSZ];
  __shared__ float degf[BSZ];
  int tid = threadIdx.x, b = blockIdx.x;
  int bstart = b * SLAB_D;
  int bend = cursD_g[b];
  int cnt = bend - bstart;
  for (int k = tid; k < cnt; k += CSRT) seg[k] = gD[bstart + k];
  if (tid < BSZ) { hist[tid] = 0; degf[tid] = 0.f; }
  __syncthreads();
  for (int k = tid; k < cnt; k += CSRT) {
    int dl = (unsigned)seg[k].x >> 24;
    atomicAdd(&hist[dl], 1);
    atomicAdd(&degf[dl], __int_as_float(seg[k].y));
  }
  __syncthreads();
  int v = (tid < BSZ) ? hist[tid] : 0;
  for (int o = 1; o < BSZ; o <<= 1) {
    int t = (tid < BSZ && tid >= o) ? hist[tid - o] : 0;
    __syncthreads();
    if (tid < BSZ) hist[tid] += t;
    __syncthreads();
  }
  if (tid < BSZ) {
    int excl = hist[tid] - v;
    curs[tid] = excl;
    int node = b * BSZ + tid;
    if (node < N) {
      off[node] = bstart + excl;
      degN[node] = v;
      dinv[node] = rsqrtf(1.0f + degf[tid]);
    }
  }
  __syncthreads();
  for (int k = tid; k < cnt; k += CSRT) {
    int2 ev = seg[k];
    int dl = (unsigned)ev.x >> 24;
    int slot = atomicAdd(&curs[dl], 1);
    gD[bstart + slot] = make_int2(ev.x & 0xFFFFFF, ev.y);
  }
}

// ------- per-src-slab weighted out-degree (dw) + global max -------
__global__ void k_dw(const unsigned* __restrict__ gS, const int* __restrict__ cursS_g,
                     float* __restrict__ dw, unsigned* maxbits, int NBS, int N) {
  __shared__ float acc[BSZS];
  int tid = threadIdx.x, b = blockIdx.x;
  int bstart = b * SLAB_S;
  int bend = cursS_g[b];
  acc[tid] = 0.f;
  __syncthreads();
  for (int k = bstart + tid; k < bend; k += BSZS) {
    unsigned p = gS[k];
    atomicAdd(&acc[p >> 16], __half2float(__ushort_as_half((unsigned short)(p & 0xFFFFu))));
  }
  __syncthreads();
  float m = 0.f;
  int node = b * BSZS + tid;
  if (node < N) { dw[node] = acc[tid]; m = acc[tid]; }
  for (int mm = 32; mm; mm >>= 1) m = fmaxf(m, __shfl_xor(m, mm, 64));
  if ((tid & 63) == 0) atomicMax(maxbits, __float_as_uint(m));
}

// ------- g0 = dinv[i] * (x @ W1) row, MFMA 16x16x32 bf16, stored fp8 e4m3 -------
// A: row=l&15, k=(l>>4)*8+i ; B: col=l&15, k=(l>>4)*8+i ; D: col=l&15, row=(l>>4)*4+reg
__global__ void k_gemm1(const float* __restrict__ x, const float* __restrict__ W1,
                        const float* __restrict__ dinv, unsigned char* __restrict__ g0, int N) {
  int lane = threadIdx.x & 63;
  int wid = (blockIdx.x * blockDim.x + threadIdx.x) >> 6;
  int nw = (gridDim.x * blockDim.x) >> 6;
  int l16 = lane & 15, lh = lane >> 4;
  bf16x8 bfrag[4][4];
#pragma unroll
  for (int cb = 0; cb < 4; ++cb)
#pragma unroll
    for (int kf = 0; kf < 4; ++kf)
#pragma unroll
      for (int i = 0; i < 8; ++i) {
        int k = kf * 32 + lh * 8 + i;
        bfrag[cb][kf][i] = f32_bf16(W1[k * F_HID + cb * 16 + l16]);
      }
  int ntiles = (N + 15) >> 4;
  for (int t = wid; t < ntiles; t += nw) {
    int rowbase = t << 4;
    int row = min(rowbase + l16, N - 1);
    bf16x8 afrag[4];
#pragma unroll
    for (int kf = 0; kf < 4; ++kf) {
      const f32x4* xp = (const f32x4*)(x + (size_t)row * F_IN + kf * 32 + lh * 8);
      f32x4 v0 = xp[0], v1 = xp[1];
#pragma unroll
      for (int i = 0; i < 4; ++i) afrag[kf][i] = f32_bf16(v0[i]);
#pragma unroll
      for (int i = 0; i < 4; ++i) afrag[kf][4 + i] = f32_bf16(v1[i]);
    }
    f32x4 acc[4] = {{0.f,0.f,0.f,0.f},{0.f,0.f,0.f,0.f},{0.f,0.f,0.f,0.f},{0.f,0.f,0.f,0.f}};
#pragma unroll
    for (int cb = 0; cb < 4; ++cb)
#pragma unroll
      for (int kf = 0; kf < 4; ++kf)
        acc[cb] = __builtin_amdgcn_mfma_f32_16x16x32_bf16(afrag[kf], bfrag[cb][kf], acc[cb], 0, 0, 0);
    if (rowbase + 16 <= N) {
      f32x4 dv = *(const f32x4*)(dinv + rowbase + lh * 4);
#pragma unroll
      for (int cb = 0; cb < 4; ++cb)
#pragma unroll
        for (int r = 0; r < 4; ++r) {
          int rr = rowbase + lh * 4 + r;
          g0[(size_t)rr * F_HID + cb * 16 + l16] = f32_to_fp8(acc[cb][r] * dv[r]);
        }
    } else {
#pragma unroll
      for (int cb = 0; cb < 4; ++cb)
#pragma unroll
        for (int r = 0; r < 4; ++r) {
          int rr = rowbase + lh * 4 + r;
          if (rr < N)
            g0[(size_t)rr * F_HID + cb * 16 + l16] = f32_to_fp8(acc[cb][r] * dinv[rr]);
        }
    }
  }
}

// ------- layer-1 agg: wave per node; 8 edge-slots x 8 lanes x 8 features; pk-fma -------
__global__ void k_agg1(const unsigned char* __restrict__ g0, const float* __restrict__ dinv,
                       const int* __restrict__ off, const int* __restrict__ degN,
                       const int2* __restrict__ csr,
                       const float* __restrict__ b1, const float* __restrict__ W2,
                       float* __restrict__ u, int N) {
  int lane = threadIdx.x & 63;
  int grp = lane >> 3;        // edge slot 0..7
  int l8  = lane & 7;         // feature octet 0..7
  int i = (blockIdx.x * blockDim.x + threadIdx.x) >> 6;
  if (i >= N) return;
  const uint2* g0v = (const uint2*)g0;
  f32x2 acc2[4] = {{0.f,0.f},{0.f,0.f},{0.f,0.f},{0.f,0.f}};
  if (grp == 0) {             // self contribution once (group 0)
    uint2 rv = g0v[(size_t)i * 8 + l8];
    acc2[0] += __builtin_amdgcn_cvt_pk_f32_fp8(rv.x, false);
    acc2[1] += __builtin_amdgcn_cvt_pk_f32_fp8(rv.x, true);
    acc2[2] += __builtin_amdgcn_cvt_pk_f32_fp8(rv.y, false);
    acc2[3] += __builtin_amdgcn_cvt_pk_f32_fp8(rv.y, true);
  }
  int p0 = off[i], p1 = p0 + degN[i];
  for (int p = p0; p < p1; p += 64) {
    int m = min(p1 - p, 64);
    int2 ed = make_int2(0, 0);
    if (lane < m) ed = csr[p + lane];
    int jmax = (m + 7) >> 3;              // dynamic: skip fully-empty edge slots
    for (int jj = 0; jj < jmax; ++jj) {
      int j = jj * 8 + grp;
      int s = __shfl(ed.x, j, 64);
      float w = __int_as_float(__shfl(ed.y, j, 64));
      if (j < m) {
        uint2 rv = g0v[(size_t)s * 8 + l8];
        f32x2 w2; w2.x = w; w2.y = w;
        acc2[0] = __builtin_elementwise_fma(__builtin_amdgcn_cvt_pk_f32_fp8(rv.x, false), w2, acc2[0]);
        acc2[1] = __builtin_elementwise_fma(__builtin_amdgcn_cvt_pk_f32_fp8(rv.x, true),  w2, acc2[1]);
        acc2[2] = __builtin_elementwise_fma(__builtin_amdgcn_cvt_pk_f32_fp8(rv.y, false), w2, acc2[2]);
        acc2[3] = __builtin_elementwise_fma(__builtin_amdgcn_cvt_pk_f32_fp8(rv.y, true),  w2, acc2[3]);
      }
    }
  }
  float acc[8] = {acc2[0].x, acc2[0].y, acc2[1].x, acc2[1].y,
                  acc2[2].x, acc2[2].y, acc2[3].x, acc2[3].y};
#pragma unroll
  for (int k = 0; k < 8; ++k) {
    acc[k] += __shfl_xor(acc[k], 8, 64);
    acc[k] += __shfl_xor(acc[k], 16, 64);
    acc[k] += __shfl_xor(acc[k], 32, 64);
  }
  float di = dinv[i];
  float pdt = 0.f;
#pragma unroll
  for (int k = 0; k < 8; ++k) {
    int f = l8 * 8 + k;
    float h = fmaxf(di * acc[k] + b1[f], 0.f);
    pdt = fmaf(h, W2[f], pdt);
  }
  pdt += __shfl_xor(pdt, 1, 64);
  pdt += __shfl_xor(pdt, 2, 64);
  pdt += __shfl_xor(pdt, 4, 64);
  if (lane == 0) u[i] = di * pdt;
}

// ------- layer-2 agg + final: 2 nodes per wave (32-lane groups) -------
__global__ void k_agg2_final(const float* __restrict__ u, const float* __restrict__ dinv,
                             const int* __restrict__ off, const int* __restrict__ degN,
                             const int2* __restrict__ csr,
                             const float* __restrict__ b2, const float* __restrict__ dw,
                             const unsigned* __restrict__ maxbits,
                             float* __restrict__ out, int N) {
  int lane32 = threadIdx.x & 31;
  int i = blockIdx.x * 8 + (threadIdx.x >> 5);   // 8 nodes per 256-thread block
  if (i >= N) return;
  float acc = (lane32 == 0) ? u[i] : 0.f;        // self (u_i)
  int p0 = off[i], p1 = p0 + degN[i];
  for (int p = p0 + lane32; p < p1; p += 32) {
    int2 ed = csr[p];
    acc = fmaf(__int_as_float(ed.y), u[ed.x], acc);
  }
  for (int mm = 16; mm; mm >>= 1) acc += __shfl_xor(acc, mm, 64);
  if (lane32 == 0) {
    float md = __uint_as_float(*maxbits);
    float z = dinv[i] * acc + b2[0];
    float sc = 1.0f / (1.0f + expf(-z));
    out[i] = sc * (1.0f + dw[i] / md);
  }
}

extern "C" void kernel_launch(void* const* d_in, const int* in_sizes, int n_in,
                              void* d_out, int out_size, void* d_ws, size_t ws_size,
                              hipStream_t stream) {
  const float* x  = (const float*)d_in[0];
  const int*   ei = (const int*)d_in[1];
  const float* ew = (const float*)d_in[2];
  const float* W1 = (const float*)d_in[3];
  const float* b1 = (const float*)d_in[4];
  const float* W2 = (const float*)d_in[5];
  const float* b2 = (const float*)d_in[6];
  float* out = (float*)d_out;

  int N = out_size;      // 100000
  int E = in_sizes[2];   // 3200000
  const int* src = ei;
  const int* dst = ei + E;

  int NBD = (N + BSZ - 1) >> BSH;       // 782
  int NBS = (N + BSZS - 1) >> BSHS;     // 98
  size_t slabD = (size_t)NBD * SLAB_D;  // 3.60M entries
  size_t slabS = (size_t)NBS * SLAB_S;  // 3.41M entries

  char* w8 = (char*)d_ws;
  int2*     gD    = (int2*)w8;                        // slabD int2 (28.8 MB; becomes CSR)
  unsigned* gS    = (unsigned*)(gD + slabD);          // slabS u32 (13.6 MB)
  unsigned char* g0 = (unsigned char*)(gS + slabS);   // N*64 fp8 (6.4 MB)
  int*      cursD = (int*)(g0 + (size_t)N * F_HID);   // NBD
  int*      cursS = cursD + NBD;                      // NBS
  int*      off   = cursS + NBS;                      // N
  int*      degN  = off + N;                          // N
  float*    dinv  = (float*)(degN + N);               // N
  float*    dw    = dinv + N;                         // N
  float*    u     = dw + N;                           // N
  unsigned* maxbits = (unsigned*)(u + N);             // 1

  k_init0<<<1, 1024, 0, stream>>>(cursD, cursS, maxbits, NBD, NBS);
  k_part<<<NWG, PT, 0, stream>>>(src, dst, ew, cursD, cursS, gD, gS, NBD, NBS, E);
  k_csr<<<NBD, CSRT, 0, stream>>>(gD, cursD, off, degN, dinv, NBD, N);
  k_dw<<<NBS, BSZS, 0, stream>>>(gS, cursS, dw, maxbits, NBS, N);
  k_gemm1<<<256, 256, 0, stream>>>(x, W1, dinv, g0, N);
  k_agg1<<<(N * 64 + 255) / 256, 256, 0, stream>>>(g0, dinv, off, degN, gD, b1, W2, u, N);
  k_agg2_final<<<(N + 7) / 8, 256, 0, stream>>>(u, dinv, off, degN, gD, b2, dw, maxbits, out, N);
}